// Round 16
// baseline (46.563 us; speedup 1.0000x reference)
//
#include <hip/hip_runtime.h>

#define BB 32
#define NN 512
#define PP 128
#define MM (BB * NN)  // 16384 rows

typedef unsigned int u32;
typedef unsigned short u16;

typedef __attribute__((ext_vector_type(8))) short short8v;  // 8 bf16 (4 VGPR)
typedef __attribute__((ext_vector_type(4))) float f32x4;

// ---- ws layout (r15 verbatim) ----
#define UVB_OFF (16 * MM)               // u[128], v[128], bias[128]
#define MUTHI_OFF ((size_t)20971520)    // u16 [BB][PP][NN] = 4 MB (muT hi)
#define MUTLO_OFF ((size_t)25165824)    // u16 [BB][PP][NN] = 4 MB (muT lo)
#define W2T_OFF ((size_t)29360128)      // u16 [PP][PP] = 32 KB (W2T[p][q]=bf16(W2[q][p]))

__device__ inline u32 bf16rne(float f) {
    u32 u = __float_as_uint(f);
    return (u + 0x7FFFu + ((u >> 16) & 1u)) >> 16;
}

// aux (r15 verbatim): bid<256: mu transpose -> muT hi/lo bf16; 256: uv+bias;
// 257: W2T bf16.
__global__ __launch_bounds__(256) void k_aux(
    const float* __restrict__ mu, const float* __restrict__ W2,
    const float* __restrict__ t4, const float* __restrict__ W3,
    const float* __restrict__ b1, const float* __restrict__ b2,
    const float* __restrict__ b3, float* __restrict__ uvb,
    u16* __restrict__ muthi, u16* __restrict__ mutlo, u16* __restrict__ w2t) {
    __shared__ float tile[64][132];
    __shared__ float su[2][PP], sv[2][PP];
    int bid = blockIdx.x;
    int t = threadIdx.x;
    if (bid < 256) {
        int b = bid >> 3, i0 = (bid & 7) * 64;
        const float4* mu4 = (const float4*)(mu + ((size_t)b * NN + i0) * PP);
#pragma unroll
        for (int s = 0; s < 8; ++s) {
            int n = s * 256 + t;
            int ii = n >> 5, c4 = n & 31;
            float4 v = mu4[ii * 32 + c4];
            *(float4*)&tile[ii][c4 * 4] = v;
        }
        __syncthreads();
        int p = t >> 1, half = t & 1;
        u32* hdst = (u32*)(muthi + ((size_t)b * PP + p) * NN + i0 + half * 32);
        u32* ldst = (u32*)(mutlo + ((size_t)b * PP + p) * NN + i0 + half * 32);
#pragma unroll
        for (int e2 = 0; e2 < 16; ++e2) {
            float v0 = tile[half * 32 + 2 * e2][p];
            float v1 = tile[half * 32 + 2 * e2 + 1][p];
            u32 h0 = bf16rne(v0), h1 = bf16rne(v1);
            float l0 = v0 - __uint_as_float(h0 << 16);
            float l1 = v1 - __uint_as_float(h1 << 16);
            hdst[e2] = h0 | (h1 << 16);
            ldst[e2] = bf16rne(l0) | (bf16rne(l1) << 16);
        }
    } else if (bid == 256) {
        int p = t & 127, h = t >> 7;
        float u = 0.f, v = 0.f;
#pragma unroll 8
        for (int q = h * 64; q < h * 64 + 64; ++q) {
            float tt = t4[q];
            float w = W3[q * PP + p];
            u += fmaxf(tt, 0.f) * w;
            v += fmaxf(-tt, 0.f) * w;
        }
        su[h][p] = u;
        sv[h][p] = v;
        __syncthreads();
        if (t < PP) {
            uvb[p] = su[0][p] + su[1][p];
            uvb[PP + p] = sv[0][p] + sv[1][p];
            uvb[2 * PP + p] = b1[p] + b2[p] + b3[p];
        }
    } else {
#pragma unroll 4
        for (int c = 0; c < 64; ++c) {
            int n = c * 256 + t;
            int q = n >> 7, pp = n & 127;
            w2t[pp * PP + q] = (u16)bf16rne(W2[q * PP + pp]);
        }
    }
}

// fused (swapped-operand phase 1): aggT[p][j] = sum_k muT[p][k] * adj[j][k]
// (adj symmetric). A = muT hi/lo DIRECT FROM GLOBAL (no LDS); B = adjL rows.
// Then agg hi/lo -> LDS (transposed store), @W2 (r15 verbatim), epilogue.
// 512 blocks = 32 b x 16 j-tiles(32); 512 thr = 8 waves; wave w: p-slice 16.
__global__ __launch_bounds__(512) void k_fused(
    const float* __restrict__ adjF, const float* __restrict__ weight,
    const u16* __restrict__ muthi, const u16* __restrict__ mutlo,
    const u16* __restrict__ w2t, const float* __restrict__ x,
    const float* __restrict__ W1, const float* __restrict__ uvb,
    float* __restrict__ out) {
    __shared__ __align__(16) u16 pool[24576];  // 48 KB
    // phase1 carve: adjL [32][72] @0 (4.5 KB). No mu staging.
    u16* adjL = pool;
    // phase2 carve (aliases, barrier-separated): w2L [128][128 swz] @0;
    // ahiL [32][128 swz] @16384; aloL @20480
    u16* w2L = pool;
    u16* ahiL = pool + 16384;
    u16* aloL = pool + 20480;
    __shared__ float psP[16][33], ngP[16][33];  // padded: no bank conflicts
    __shared__ float psF[32], ngF[32];

    int bid = blockIdx.x;
    int vbid = ((bid & 7) << 6) | (bid >> 3);  // XCD chunking (bijective)
    int b = vbid >> 4;
    int j0 = (vbid & 15) * 32;
    int tx = threadIdx.x, lane = tx & 63, w = tx >> 6;

    const float* adjrow = adjF + ((size_t)b * NN + j0) * NN;  // [j][i] rows
    const float* adjcol = adjF + (size_t)b * NN * NN + j0;     // [i][j] cols
    const float* wcol = weight + (size_t)b * NN * NN + j0;     // [i][j] cols
    const u16* mhG = muthi + (size_t)b * PP * NN;
    const u16* mlG = mutlo + (size_t)b * PP * NN;

    // pos/neg mapping: jw = tx&31, kgrp = tx>>5 (16 groups x 4 i's per step)
    int jw = tx & 31, kgrp = tx >> 5;
    float ps = 0.f, ng = 0.f;

    // A-fragment row (muT row = global p) for this lane
    int prow = w * 16 + (lane & 15);
    const u16* mhRow = mhG + (size_t)prow * NN + (lane >> 4) * 8;
    const u16* mlRow = mlG + (size_t)prow * NN + (lane >> 4) * 8;

    f32x4 acc[2];  // [jt]; D' = aggT: row=p-local, col=j-local(jt*16+lane&15)
    acc[0] = (f32x4){0.f, 0.f, 0.f, 0.f};
    acc[1] = (f32x4){0.f, 0.f, 0.f, 0.f};

    for (int step = 0; step < 8; ++step) {
        int k0 = step * 64;
        // prefetch A fragments for this step (independent of LDS/barriers)
        short8v ah0 = *(const short8v*)(mhRow + k0);
        short8v al0 = *(const short8v*)(mlRow + k0);
        short8v ah1 = *(const short8v*)(mhRow + k0 + 32);
        short8v al1 = *(const short8v*)(mlRow + k0 + 32);
        {  // stage adj tile 32x64 from f32, inline 0/1 -> bf16 (1 float4/thread)
            int jj = tx >> 4, kk0 = (tx & 15) * 4;
            float4 f0 = *(const float4*)(adjrow + (size_t)jj * NN + k0 + kk0);
            uint2 o;
            o.x = (f0.x != 0.f ? 0x3F80u : 0u) | (f0.y != 0.f ? 0x3F800000u : 0u);
            o.y = (f0.z != 0.f ? 0x3F80u : 0u) | (f0.w != 0.f ? 0x3F800000u : 0u);
            *(uint2*)&adjL[jj * 72 + kk0] = o;
        }
        {  // inline pos/neg: weight+adj column slices (coalesced 128B segments)
#pragma unroll
            for (int kk = 0; kk < 4; ++kk) {
                size_t off = (size_t)(k0 + kgrp * 4 + kk) * NN + jw;
                float wv = wcol[off];
                float av = adjcol[off];  // exactly 0.0 or 1.0
                ps += fmaxf(wv, 0.f) * av;
                ng += fmaxf(-wv, 0.f) * av;
            }
        }
        __syncthreads();
        // MFMA: B = adjL rows (col=j=lane&15, k contiguous — valid since adj
        // is symmetric: adjT[k][j] == adj[j][k])
        {
            short8v b0 = *(const short8v*)&adjL[(0 * 16 + (lane & 15)) * 72 + (lane >> 4) * 8];
            short8v b1v = *(const short8v*)&adjL[(1 * 16 + (lane & 15)) * 72 + (lane >> 4) * 8];
            acc[0] = __builtin_amdgcn_mfma_f32_16x16x32_bf16(ah0, b0, acc[0], 0, 0, 0);
            acc[0] = __builtin_amdgcn_mfma_f32_16x16x32_bf16(al0, b0, acc[0], 0, 0, 0);
            acc[1] = __builtin_amdgcn_mfma_f32_16x16x32_bf16(ah0, b1v, acc[1], 0, 0, 0);
            acc[1] = __builtin_amdgcn_mfma_f32_16x16x32_bf16(al0, b1v, acc[1], 0, 0, 0);
            short8v b2 = *(const short8v*)&adjL[(0 * 16 + (lane & 15)) * 72 + 32 + (lane >> 4) * 8];
            short8v b3v = *(const short8v*)&adjL[(1 * 16 + (lane & 15)) * 72 + 32 + (lane >> 4) * 8];
            acc[0] = __builtin_amdgcn_mfma_f32_16x16x32_bf16(ah1, b2, acc[0], 0, 0, 0);
            acc[0] = __builtin_amdgcn_mfma_f32_16x16x32_bf16(al1, b2, acc[0], 0, 0, 0);
            acc[1] = __builtin_amdgcn_mfma_f32_16x16x32_bf16(ah1, b3v, acc[1], 0, 0, 0);
            acc[1] = __builtin_amdgcn_mfma_f32_16x16x32_bf16(al1, b3v, acc[1], 0, 0, 0);
        }
        __syncthreads();
    }

    // pos/neg partials -> LDS; aggT -> agg hi/lo LDS (transposed store, XOR-swz);
    // stage W2T (same swz, r15 verbatim)
    psP[kgrp][jw] = ps;
    ngP[kgrp][jw] = ng;
    {
#pragma unroll
        for (int jt = 0; jt < 2; ++jt)
#pragma unroll
            for (int r = 0; r < 4; ++r) {
                int j = jt * 16 + (lane & 15);          // D' col = j-local
                int q = w * 16 + (lane >> 4) * 4 + r;   // D' row = p (= agg q)
                float v = acc[jt][r];
                u32 h = bf16rne(v);
                float lf = v - __uint_as_float(h << 16);
                int qs = q ^ ((j & 7) << 3);
                ahiL[j * 128 + qs] = (u16)h;
                aloL[j * 128 + qs] = (u16)bf16rne(lf);
            }
        int p = tx >> 2, c4 = tx & 3;
#pragma unroll
        for (int c = 0; c < 4; ++c) {
            int cc = c4 * 4 + c;
            int q8 = (cc * 8) ^ ((p & 7) << 3);
            *(uint4*)&w2L[p * 128 + q8] = *(const uint4*)(w2t + p * PP + cc * 8);
        }
    }
    __syncthreads();

    // final pos/neg reduce (32 threads)
    if (tx < 32) {
        float P = 0.f, Ng = 0.f;
#pragma unroll
        for (int g = 0; g < 16; ++g) {
            P += psP[g][tx];
            Ng += ngP[g][tx];
        }
        psF[tx] = P;
        ngF[tx] = Ng;
    }

    // phase 2 (r15 verbatim): D2[j][p'] = sum_q agg[j][q] * W2[q][p']
    f32x4 acc2[2];
    acc2[0] = (f32x4){0.f, 0.f, 0.f, 0.f};
    acc2[1] = (f32x4){0.f, 0.f, 0.f, 0.f};
#pragma unroll
    for (int ks = 0; ks < 4; ++ks) {
        int kb = ks * 32 + (lane >> 4) * 8;
        int prow2 = w * 16 + (lane & 15);
        short8v bfr = *(const short8v*)&w2L[prow2 * 128 + (kb ^ ((prow2 & 7) << 3))];
#pragma unroll
        for (int jt = 0; jt < 2; ++jt) {
            int jrow = jt * 16 + (lane & 15);
            short8v ah = *(const short8v*)&ahiL[jrow * 128 + (kb ^ ((jrow & 7) << 3))];
            short8v al = *(const short8v*)&aloL[jrow * 128 + (kb ^ ((jrow & 7) << 3))];
            acc2[jt] = __builtin_amdgcn_mfma_f32_16x16x32_bf16(ah, bfr, acc2[jt], 0, 0, 0);
            acc2[jt] = __builtin_amdgcn_mfma_f32_16x16x32_bf16(al, bfr, acc2[jt], 0, 0, 0);
        }
    }
    __syncthreads();  // psF/ngF visible to all

    // epilogue (r15 verbatim): wave w owns p' in [16w, 16w+16)
    int pp = w * 16 + (lane & 15);
    float u_ = uvb[pp];
    float v_ = uvb[PP + pp];
    float bb_ = uvb[2 * PP + pp];
    float w1_ = W1[pp];
    int row0 = b * NN + j0;
#pragma unroll
    for (int jt = 0; jt < 2; ++jt)
#pragma unroll
        for (int r = 0; r < 4; ++r) {
            int jloc = jt * 16 + (lane >> 4) * 4 + r;
            int row = row0 + jloc;
            float xs = x[row];
            float o = acc2[jt][r] + xs * w1_ + psF[jloc] * u_ + ngF[jloc] * v_ + bb_;
            out[(size_t)row * PP + pp] = fmaxf(o, 0.f);
        }
}

extern "C" void kernel_launch(void* const* d_in, const int* in_sizes, int n_in,
                              void* d_out, int out_size, void* d_ws, size_t ws_size,
                              hipStream_t stream) {
    const float* x      = (const float*)d_in[0];
    const float* mu     = (const float*)d_in[1];
    const float* weight = (const float*)d_in[2];
    const float* adj    = (const float*)d_in[3];
    const float* W1     = (const float*)d_in[4];
    const float* b1     = (const float*)d_in[5];
    const float* W2     = (const float*)d_in[6];
    const float* b2     = (const float*)d_in[7];
    const float* W3     = (const float*)d_in[8];
    const float* b3     = (const float*)d_in[9];
    const float* theta4 = (const float*)d_in[10];
    float* out = (float*)d_out;

    float* ws  = (float*)d_ws;
    float* uvb = ws + UVB_OFF;
    u16* muthi = (u16*)((char*)d_ws + MUTHI_OFF);
    u16* mutlo = (u16*)((char*)d_ws + MUTLO_OFF);
    u16* w2t   = (u16*)((char*)d_ws + W2T_OFF);

    k_aux<<<258, 256, 0, stream>>>(mu, W2, theta4, W3, b1, b2, b3, uvb,
                                   muthi, mutlo, w2t);

    k_fused<<<512, 512, 0, stream>>>(adj, weight, muthi, mutlo, w2t, x, W1,
                                     uvb, out);
}